// Round 18
// baseline (290.056 us; speedup 1.0000x reference)
//
#include <hip/hip_runtime.h>

// RelativeMultiHeadAttention (B=8, T=2048, D_MODEL=1024, H=16, D_HEAD=64)
// Round 18: QKV via gemm15 = 128x384 tile, BK=32, 2-region 64KB LDS
// (2 blocks/CU kept), reg-pipelined frags (gemm9's green body), VMC(0)
// drain hidden under 24-MFMA cluster. -17% LDS-port bytes/FLOP vs 128x256.
// P & O: gemm12 (BK=64, green). Attention: MFMA-based (R7).
// rel_shift: shifted[m]=pos_score[f=m+8 flat (b*(T+1)+t)]:
//   b_s=f/2049, t_s=f%2049; zero if t_s==0 else (b_s,t_s-1).

typedef __attribute__((ext_vector_type(8))) short short8;
typedef __attribute__((ext_vector_type(4))) float f32x4;

__device__ __forceinline__ ushort f2bf(float f) {
    unsigned u = __float_as_uint(f);
    u += 0x7FFFu + ((u >> 16) & 1u);   // round-to-nearest-even
    return (ushort)(u >> 16);
}
__device__ __forceinline__ float bf2f(ushort u) {
    return __uint_as_float(((unsigned)u) << 16);
}

typedef const unsigned int __attribute__((address_space(1)))* gas_t;
typedef unsigned int __attribute__((address_space(3)))* las_t;
__device__ __forceinline__ void gl_lds16(const ushort* g, ushort* l) {
    __builtin_amdgcn_global_load_lds((gas_t)g, (las_t)l, 16, 0, 0);
}

// ---------------- f32 -> bf16 convert (8 elems/thread) ----------------
__global__ __launch_bounds__(256)
void conv_bf16_k(const float* __restrict__ in, ushort* __restrict__ out)
{
    const size_t i = ((size_t)blockIdx.x * 256 + threadIdx.x) * 8;
    float4 a = *(const float4*)(in + i);
    float4 b = *(const float4*)(in + i + 4);
    short8 o = {(short)f2bf(a.x), (short)f2bf(a.y), (short)f2bf(a.z), (short)f2bf(a.w),
                (short)f2bf(b.x), (short)f2bf(b.y), (short)f2bf(b.z), (short)f2bf(b.w)};
    *(short8*)(out + i) = o;
}

// ---------------- fused 5x Wt[n][k] = bf16(W[k][n]) ----------------
__global__ __launch_bounds__(256)
void transpose5_k(const float* __restrict__ W0, const float* __restrict__ W1,
                  const float* __restrict__ W2, const float* __restrict__ W3,
                  const float* __restrict__ W4, ushort* __restrict__ Wt)
{
    __shared__ float tile[32][33];
    const int z = blockIdx.z;
    const float* W = (z == 0) ? W0 : (z == 1) ? W1 : (z == 2) ? W2 : (z == 3) ? W3 : W4;
    ushort* dst = Wt + (size_t)z * 1024 * 1024;
    const int tx = threadIdx.x & 31;
    const int ty = threadIdx.x >> 5;   // 0..7
    const int n0 = blockIdx.x * 32;
    const int k0 = blockIdx.y * 32;
#pragma unroll
    for (int i = 0; i < 4; ++i)
        tile[ty + i * 8][tx] = W[(size_t)(k0 + ty + i * 8) * 1024 + n0 + tx];
    __syncthreads();
#pragma unroll
    for (int i = 0; i < 4; ++i)
        dst[(size_t)(n0 + ty + i * 8) * 1024 + k0 + tx] = f2bf(tile[tx][ty + i * 8]);
}

// ---------------- bias concat [bq;bk;bv] ----------------
__global__ __launch_bounds__(256)
void bias_concat_k(const float* __restrict__ b0, const float* __restrict__ b1,
                   const float* __restrict__ b2, float* __restrict__ out)
{
    const int i = blockIdx.x * 256 + threadIdx.x;   // 0..3071
    const int s = i >> 10;
    const int j = i & 1023;
    out[i] = (s == 0) ? b0[j] : (s == 1) ? b1[j] : b2[j];
}

#define VMC(n) asm volatile("s_waitcnt vmcnt(" #n ")" ::: "memory")
#define KDIM 1024

// ======== gemm15: 128x384, BK=32, 2-region 64KB LDS, reg-pipelined ========
// 512 thr = 8 waves (2x4); per-wave C: 64x96 (4x6 frags), acc 96 VGPR.
// LDS: A [2][128][32]=16KB + B [2][384][32]=48KB = 64KB -> 2 blocks/CU.
// Swizzle (gemm9's, 32-col rows): scol=((tid&3)^((tid>>3)&3))*8,
//   fb=((l>>4)^((l>>1)&3))*8.
// Body t: STAGE(t+1) [1 A + 3 B gl_lds]; ds_read(t)->frag[t&1] (A4+B6);
//   MFMA(t-1)<-frag[(t-1)&1] (reg-only, hides drain); VMC(0) [stage(t+1)
//   landed]; lgkm(0) [reads drained -> region overwrite safe]; barrier.
// Region safety (2 regions): STAGE(t+1) writes region (t+1)&1 which held
//   tile t-1, whose reads drained at body t-1's lgkm(0) pre-barrier.

template<int HAS_BIAS, int OUT_BF16>
__global__ __launch_bounds__(512, 2)
void gemm15_k(const ushort* __restrict__ A, const ushort* __restrict__ Bt,
              const float* __restrict__ bias, void* __restrict__ Cv,
              int N)
{
    __shared__ ushort As[2 * 4096];    // 16KB: [2][128][32]
    __shared__ ushort Bs[2 * 12288];   // 48KB: [2][384][32]
    const int tid = threadIdx.x;
    const int l = tid & 63;
    const int w = tid >> 6;
    const int wr = w >> 2;             // 0..1 (m 64-half)
    const int wc = w & 3;              // 0..3 (n 96-quarter)

    // XCD/L2-aware bijective remap (gx%4==0, gy%8==0)
    const int gx = gridDim.x;
    const int lin = blockIdx.y * gx + blockIdx.x;
    const int xcd = lin & 7;
    const int idx = lin >> 3;
    const int hb = gridDim.y >> 3;
    const int sxc = gx >> 2;
    const int g4 = idx >> 4;
    const int li = idx & 15;
    const int bx = (g4 % sxc) * 4 + (li & 3);
    const int by = xcd * hb + (g4 / sxc) * 4 + (li >> 2);
    const int bm = by * 128;
    const int bn = bx * 384;

    const int srow = tid >> 2;         // 0..127
    const int scol = ((tid & 3) ^ ((tid >> 3) & 3)) * 8;
    const ushort* Ag  = A  + (size_t)(bm + srow) * KDIM + scol;
    const ushort* Bg  = Bt + (size_t)(bn + srow) * KDIM + scol;
    const ushort* Bg2 = Bg + (size_t)128 * KDIM;
    const ushort* Bg3 = Bg + (size_t)256 * KDIM;
    const int lw = w * 512;

    const int lr = l & 15;
    const int fb = (((l >> 4) ^ ((l >> 1) & 3)) * 8);
    const int laneA = (wr * 64 + lr) * 32 + fb;
    const int laneB = (wc * 96 + lr) * 32 + fb;

    f32x4 acc[4][6];
#pragma unroll
    for (int i = 0; i < 4; ++i)
#pragma unroll
        for (int n = 0; n < 6; ++n)
            acc[i][n] = (f32x4){0.f, 0.f, 0.f, 0.f};

    short8 fa[2][4], fbv[2][6];   // parity-indexed frag double-buffer (static idx)

#define STAGE15(tt, rg) do { \
    ushort* ha = As + (rg) * 4096 + lw; \
    ushort* hbp = Bs + (rg) * 12288 + lw; \
    const size_t ko = (size_t)(tt) * 32; \
    gl_lds16(Ag + ko, ha); \
    gl_lds16(Bg + ko, hbp); \
    gl_lds16(Bg2 + ko, hbp + 4096); \
    gl_lds16(Bg3 + ko, hbp + 8192); \
} while (0)

    // prologue: stage t0->r0; land; barrier
    STAGE15(0, 0);
    VMC(0);
    __builtin_amdgcn_s_barrier();
    __builtin_amdgcn_sched_barrier(0);

#pragma unroll
    for (int t = 0; t < 32; ++t) {
        const int cur = t & 1;
        const int pb = t & 1;          // frag buffer for tile t (static)
        if (t + 1 < 32) STAGE15(t + 1, (t + 1) & 1);
        const ushort* ap = As + cur * 4096 + laneA;
        const ushort* bp = Bs + cur * 12288 + laneB;
#pragma unroll
        for (int m = 0; m < 4; ++m) fa[pb][m] = *(const short8*)(ap + m * 512);
#pragma unroll
        for (int n = 0; n < 6; ++n) fbv[pb][n] = *(const short8*)(bp + n * 512);
        if (t > 0) {
            const int qb2 = (t - 1) & 1;
#pragma unroll
            for (int m = 0; m < 4; ++m)
#pragma unroll
                for (int n = 0; n < 6; ++n)
                    acc[m][n] = __builtin_amdgcn_mfma_f32_16x16x32_bf16(fa[qb2][m], fbv[qb2][n], acc[m][n], 0, 0, 0);
        }
        VMC(0);
        asm volatile("s_waitcnt lgkmcnt(0)" ::: "memory");
        __builtin_amdgcn_s_barrier();
        __builtin_amdgcn_sched_barrier(0);
    }
    // final tile 31 MFMA (frag buffer 31&1 = 1)
#pragma unroll
    for (int m = 0; m < 4; ++m)
#pragma unroll
        for (int n = 0; n < 6; ++n)
            acc[m][n] = __builtin_amdgcn_mfma_f32_16x16x32_bf16(fa[1][m], fbv[1][n], acc[m][n], 0, 0, 0);
#undef STAGE15

    // epilogue: C/D layout col=lane&15, row=(lane>>4)*4+reg
    const int cr = (l >> 4) * 4;
    const int cc = l & 15;
    float bv[6];
#pragma unroll
    for (int n = 0; n < 6; ++n)
        bv[n] = HAS_BIAS ? bias[bn + wc * 96 + n * 16 + cc] : 0.f;
#pragma unroll
    for (int m = 0; m < 4; ++m) {
#pragma unroll
        for (int n = 0; n < 6; ++n) {
            const int col = bn + wc * 96 + n * 16 + cc;
#pragma unroll
            for (int r = 0; r < 4; ++r) {
                const int row = bm + wr * 64 + m * 16 + cr + r;
                float v = acc[m][n][r] + bv[n];
                if (OUT_BF16) ((ushort*)Cv)[(size_t)row * N + col] = f2bf(v);
                else          ((float*)Cv)[(size_t)row * N + col] = v;
            }
        }
    }
}

// ======== gemm12: 128x256, BK=64, 3-region 144KB LDS (R16, green) ========
template<int HAS_BIAS, int OUT_BF16>
__global__ __launch_bounds__(512, 2)
void gemm12_k(const ushort* __restrict__ A, const ushort* __restrict__ Bt,
              const float* __restrict__ bias, void* __restrict__ Cv,
              int N)
{
    __shared__ ushort As[3 * 8192];    // 48KB: [3][128][64]
    __shared__ ushort Bs[3 * 16384];   // 96KB: [3][256][64]
    const int tid = threadIdx.x;
    const int l = tid & 63;
    const int w = tid >> 6;
    const int wr = w >> 2;             // 0..1 (m 64-half)
    const int wc = w & 3;              // 0..3 (n 64-quarter)

    const int gx = gridDim.x;
    const int lin = blockIdx.y * gx + blockIdx.x;
    const int xcd = lin & 7;
    const int idx = lin >> 3;
    const int hb = gridDim.y >> 3;
    const int sxc = gx >> 2;
    const int g4 = idx >> 4;
    const int li = idx & 15;
    const int bx = (g4 % sxc) * 4 + (li & 3);
    const int by = xcd * hb + (g4 / sxc) * 4 + (li >> 2);
    const int bm = by * 128;
    const int bn = bx * 256;

    const int srow = w * 8 + (l >> 3);
    const int scol = ((l & 7) ^ ((l >> 3) & 7)) * 8;
    const ushort* Ag = A  + (size_t)(bm + srow) * KDIM + scol;
    const ushort* Bg = Bt + (size_t)(bn + srow) * KDIM + scol;
    const int lw = w * 512;

    const int lr = l & 15;
    const int fb0 = (((l >> 4)) ^ (l & 7)) * 8;
    const int fb1 = ((4 + (l >> 4)) ^ (l & 7)) * 8;
    const int laneA = (wr * 64 + lr) * 64;
    const int laneB = (wc * 64 + lr) * 64;

    f32x4 acc[4][4];
#pragma unroll
    for (int i = 0; i < 4; ++i)
#pragma unroll
        for (int n = 0; n < 4; ++n)
            acc[i][n] = (f32x4){0.f, 0.f, 0.f, 0.f};

#define STAGE12(tt, rg) do { \
    const size_t ko = (size_t)(tt) * 64; \
    ushort* ha = As + (rg) * 8192 + lw; \
    gl_lds16(Ag + ko, ha); \
    gl_lds16(Ag + (size_t)64 * KDIM + ko, ha + 4096); \
    ushort* hb2 = Bs + (rg) * 16384 + lw; \
    gl_lds16(Bg + ko, hb2); \
    gl_lds16(Bg + (size_t)64 * KDIM + ko, hb2 + 4096); \
    gl_lds16(Bg + (size_t)128 * KDIM + ko, hb2 + 8192); \
    gl_lds16(Bg + (size_t)192 * KDIM + ko, hb2 + 12288); \
} while (0)

    STAGE12(0, 0);
    STAGE12(1, 1);
    VMC(6);
    __builtin_amdgcn_s_barrier();
    __builtin_amdgcn_sched_barrier(0);

#pragma unroll
    for (int t = 0; t < 16; ++t) {
        const int cur = t % 3;
        const int stg = (t + 2) % 3;
        if (t + 2 < 16) STAGE12(t + 2, stg);
        const ushort* ap = As + cur * 8192 + laneA;
        const ushort* bp = Bs + cur * 16384 + laneB;
        short8 af0[4], af1[4], bf0[4], bf1[4];
#pragma unroll
        for (int m = 0; m < 4; ++m) {
            af0[m] = *(const short8*)(ap + m * 1024 + fb0);
            af1[m] = *(const short8*)(ap + m * 1024 + fb1);
        }
#pragma unroll
        for (int n = 0; n < 4; ++n) {
            bf0[n] = *(const short8*)(bp + n * 1024 + fb0);
            bf1[n] = *(const short8*)(bp + n * 1024 + fb1);
        }
        if (t < 14) { VMC(6); }
        else if (t == 14) { VMC(0); }
        asm volatile("s_waitcnt lgkmcnt(0)" ::: "memory");
        __builtin_amdgcn_s_barrier();
        __builtin_amdgcn_sched_barrier(0);
#pragma unroll
        for (int m = 0; m < 4; ++m)
#pragma unroll
            for (int n = 0; n < 4; ++n)
                acc[m][n] = __builtin_amdgcn_mfma_f32_16x16x32_bf16(af0[m], bf0[n], acc[m][n], 0, 0, 0);
#pragma unroll
        for (int m = 0; m < 4; ++m)
#pragma unroll
            for (int n = 0; n < 4; ++n)
                acc[m][n] = __builtin_amdgcn_mfma_f32_16x16x32_bf16(af1[m], bf1[n], acc[m][n], 0, 0, 0);
    }
#undef STAGE12

    const int cr = (l >> 4) * 4;
    const int cc = l & 15;
    float bv[4];
#pragma unroll
    for (int n = 0; n < 4; ++n)
        bv[n] = HAS_BIAS ? bias[bn + wc * 64 + n * 16 + cc] : 0.f;
#pragma unroll
    for (int m = 0; m < 4; ++m) {
#pragma unroll
        for (int n = 0; n < 4; ++n) {
            const int col = bn + wc * 64 + n * 16 + cc;
#pragma unroll
            for (int r = 0; r < 4; ++r) {
                const int row = bm + wr * 64 + m * 16 + cr + r;
                float v = acc[m][n][r] + bv[n];
                if (OUT_BF16) ((ushort*)Cv)[(size_t)row * N + col] = f2bf(v);
                else          ((float*)Cv)[(size_t)row * N + col] = v;
            }
        }
    }
}

// ---------------- MFMA attention: 1 wave = 1 timestep (R7) ----------------
__global__ __launch_bounds__(256)
void attn2_k(const ushort* __restrict__ qkv, const ushort* __restrict__ pbuf,
             const float* __restrict__ ubias, const float* __restrict__ vbias,
             const int* __restrict__ masks, ushort* __restrict__ ctx)
{
    __shared__ __align__(16) float Pl[4][16 * 20];   // per-wave P tile, stride 20

    const int tid = threadIdx.x;
    const int w = tid >> 6;
    const int l = tid & 63;
    const int m = blockIdx.x * 4 + w;
    const int b2 = m >> 11;
    const int t2 = m & 2047;
    const int f  = m + 8;
    const int bs = f / 2049;
    const int ts = f - bs * 2049;
    const bool haspos = (ts != 0);
    const int mp = bs * 2048 + ts - 1;

    const int lr = l & 15;
    const int g  = l >> 4;
    const int ko = g * 8;

    const ushort* qb = qkv + (size_t)m * 3072;

    short8 quf[2], kf[2], qvf[2], pf[2];
#pragma unroll
    for (int c = 0; c < 2; ++c) {
        const int off = lr * 64 + c * 32 + ko;
        short8 q = *(const short8*)(qb + off);
        kf[c]    = *(const short8*)(qb + 1024 + off);
        float4 u0 = *(const float4*)(ubias + off);
        float4 u1 = *(const float4*)(ubias + off + 4);
        quf[c] = (short8){
            (short)f2bf(bf2f((ushort)q[0]) + u0.x), (short)f2bf(bf2f((ushort)q[1]) + u0.y),
            (short)f2bf(bf2f((ushort)q[2]) + u0.z), (short)f2bf(bf2f((ushort)q[3]) + u0.w),
            (short)f2bf(bf2f((ushort)q[4]) + u1.x), (short)f2bf(bf2f((ushort)q[5]) + u1.y),
            (short)f2bf(bf2f((ushort)q[6]) + u1.z), (short)f2bf(bf2f((ushort)q[7]) + u1.w)};
    }
    if (haspos) {
        const ushort* qmp = qkv + (size_t)mp * 3072;
        const ushort* pp  = pbuf + (size_t)mp * 1024;
#pragma unroll
        for (int c = 0; c < 2; ++c) {
            const int off = lr * 64 + c * 32 + ko;
            short8 q = *(const short8*)(qmp + off);
            pf[c]    = *(const short8*)(pp + off);
            float4 v0 = *(const float4*)(vbias + off);
            float4 v1 = *(const float4*)(vbias + off + 4);
            qvf[c] = (short8){
                (short)f2bf(bf2f((ushort)q[0]) + v0.x), (short)f2bf(bf2f((ushort)q[1]) + v0.y),
                (short)f2bf(bf2f((ushort)q[2]) + v0.z), (short)f2bf(bf2f((ushort)q[3]) + v0.w),
                (short)f2bf(bf2f((ushort)q[4]) + v1.x), (short)f2bf(bf2f((ushort)q[5]) + v1.y),
                (short)f2bf(bf2f((ushort)q[6]) + v1.z), (short)f2bf(bf2f((ushort)q[7]) + v1.w)};
        }
    }

    f32x4 s = (f32x4){0.f, 0.f, 0.f, 0.f};
    s = __builtin_amdgcn_mfma_f32_16x16x32_bf16(quf[0], kf[0], s, 0, 0, 0);
    s = __builtin_amdgcn_mfma_f32_16x16x32_bf16(quf[1], kf[1], s, 0, 0, 0);
    if (haspos) {
        s = __builtin_amdgcn_mfma_f32_16x16x32_bf16(qvf[0], pf[0], s, 0, 0, 0);
        s = __builtin_amdgcn_mfma_f32_16x16x32_bf16(qvf[1], pf[1], s, 0, 0, 0);
    }

    const bool mk = (masks[m] != 0);
    float sc[4];
#pragma unroll
    for (int r = 0; r < 4; ++r)
        sc[r] = mk ? s[r] * 0.03125f : 1e-9f;

    float mx[4], ex[4], sm[4];
#pragma unroll
    for (int r = 0; r < 4; ++r) {
        mx[r] = sc[r];
#pragma unroll
        for (int o = 8; o; o >>= 1) mx[r] = fmaxf(mx[r], __shfl_xor(mx[r], o, 64));
        ex[r] = __expf(sc[r] - mx[r]);
        sm[r] = ex[r];
#pragma unroll
        for (int o = 8; o; o >>= 1) sm[r] += __shfl_xor(sm[r], o, 64);
    }

    float* pw = Pl[w];
#pragma unroll
    for (int r = 0; r < 4; ++r)
        pw[(g * 4 + r) * 20 + lr] = ex[r] / sm[r];

    short8 pa;
    if (g < 2) {
        float4 p0 = *(const float4*)(pw + lr * 20 + g * 8);
        float4 p1 = *(const float4*)(pw + lr * 20 + g * 8 + 4);
        pa = (short8){(short)f2bf(p0.x), (short)f2bf(p0.y), (short)f2bf(p0.z), (short)f2bf(p0.w),
                      (short)f2bf(p1.x), (short)f2bf(p1.y), (short)f2bf(p1.z), (short)f2bf(p1.w)};
    } else {
        pa = (short8){0, 0, 0, 0, 0, 0, 0, 0};
    }

    const ushort* vb0 = qb + 2048;
    const size_t orow_base = (size_t)b2 * 2048 + (t2 >> 4);
    const int ocol_base = (t2 & 15) * 64;
#pragma unroll
    for (int n = 0; n < 4; ++n) {
        const int d0 = n * 16;
        short8 vf;
        if (g < 2) {
#pragma unroll
            for (int j = 0; j < 8; ++j)
                vf[j] = (short)vb0[(ko + j) * 64 + d0 + lr];
        } else {
            vf = (short8){0, 0, 0, 0, 0, 0, 0, 0};
        }
        f32x4 o = (f32x4){0.f, 0.f, 0.f, 0.f};
        o = __builtin_amdgcn_mfma_f32_16x16x32_bf16(pa, vf, o, 0, 0, 0);
#pragma unroll
        for (int r = 0; r < 4; ++r) {
            const int h1 = g * 4 + r;
            ctx[(orow_base + (size_t)h1 * 128) * 1024 + ocol_base + d0 + lr] = f2bf(o[r]);
        }
    }
}

extern "C" void kernel_launch(void* const* d_in, const int* in_sizes, int n_in,
                              void* d_out, int out_size, void* d_ws, size_t ws_size,
                              hipStream_t stream)
{
    (void)in_sizes; (void)n_in; (void)out_size; (void)ws_size;
    const float* inputs = (const float*)d_in[0];
    const float* pos    = (const float*)d_in[1];
    const int*   masks  = (const int*)d_in[2];
    const float* Wq = (const float*)d_in[3];
    const float* bq = (const float*)d_in[4];
    const float* Wk = (const float*)d_in[5];
    const float* bk = (const float*)d_in[6];
    const float* Wv = (const float*)d_in[7];
    const float* bv = (const float*)d_in[8];
    const float* Wp = (const float*)d_in[9];
    const float* Wo = (const float*)d_in[10];
    const float* bo = (const float*)d_in[11];
    const float* ub = (const float*)d_in[12];
    const float* vb = (const float*)d_in[13];

    // ws layout:
    //   [0,10MB)      WqT|WkT|WvT|WpT|WoT  (bf16 [N][K], contiguous)
    //   [10MB,+64KB)  biascat (f32[3072])
    //   S1 (32MB): pos_bf16 -> inputs_bf16 -> ctx
    //   S2 (32MB): pbuf  (pos @ Wp, bf16)
    //   S3 (96MB): qkv   ([16384][3072] bf16)
    char* ws = (char*)d_ws;
    const size_t WT_SZ = (size_t)1024 * 1024 * 2;
    ushort* WT  = (ushort*)(ws);                 // 5 consecutive transposed weights
    ushort* WqT = WT;
    ushort* WpT = (ushort*)(ws + 3 * WT_SZ);
    ushort* WoT = (ushort*)(ws + 4 * WT_SZ);
    float*  biascat = (float*)(ws + 5 * WT_SZ);
    char* bufs = ws + 5 * WT_SZ + 65536;
    const size_t S_SZ = (size_t)16384 * 1024 * 2;       // 32MB
    ushort* S1 = (ushort*)(bufs);
    ushort* S2 = (ushort*)(bufs + S_SZ);
    ushort* S3 = (ushort*)(bufs + 2 * S_SZ);            // 96MB

    dim3 blk(256);

    // fused weight transposes (z=0..4 -> Wq,Wk,Wv,Wp,Wo) + biases
    transpose5_k<<<dim3(32, 32, 5), blk, 0, stream>>>(Wq, Wk, Wv, Wp, Wo, WT);
    bias_concat_k<<<dim3(12), blk, 0, stream>>>(bq, bk, bv, biascat);

    conv_bf16_k<<<dim3(8192), blk, 0, stream>>>(pos, S1);
    gemm12_k<0, 1><<<dim3(4, 128), dim3(512), 0, stream>>>(S1, WpT, nullptr, S2, 1024);

    conv_bf16_k<<<dim3(8192), blk, 0, stream>>>(inputs, S1);
    gemm15_k<1, 1><<<dim3(8, 128), dim3(512), 0, stream>>>(S1, WqT, biascat, S3, 3072);

    attn2_k<<<dim3(4096), blk, 0, stream>>>(S3, S2, ub, vb, masks, S1);

    gemm12_k<1, 0><<<dim3(4, 128), dim3(512), 0, stream>>>(S1, WoT, bo, (float*)d_out, 1024);
}

// Round 19
// 267.924 us; speedup vs baseline: 1.0826x; 1.0826x over previous
//
#include <hip/hip_runtime.h>

// RelativeMultiHeadAttention (B=8, T=2048, D_MODEL=1024, H=16, D_HEAD=64)
// Round 19: FINAL — revert to R16 exactly (best green, 268.4us).
// R18's 128x384 tile regressed (VGPR-bound 1 blk/CU + depth-1 prefetch).
// GEMM: 128x256, BK=64, 3-region 144KB LDS, counted VMC(6), lgkm(0)
// pre-barrier, (512,2). Attention: MFMA-based (R7).
// rel_shift: shifted[m]=pos_score[f=m+8 flat (b*(T+1)+t)]:
//   b_s=f/2049, t_s=f%2049; zero if t_s==0 else (b_s,t_s-1).

typedef __attribute__((ext_vector_type(8))) short short8;
typedef __attribute__((ext_vector_type(4))) float f32x4;

__device__ __forceinline__ ushort f2bf(float f) {
    unsigned u = __float_as_uint(f);
    u += 0x7FFFu + ((u >> 16) & 1u);   // round-to-nearest-even
    return (ushort)(u >> 16);
}
__device__ __forceinline__ float bf2f(ushort u) {
    return __uint_as_float(((unsigned)u) << 16);
}

typedef const unsigned int __attribute__((address_space(1)))* gas_t;
typedef unsigned int __attribute__((address_space(3)))* las_t;
__device__ __forceinline__ void gl_lds16(const ushort* g, ushort* l) {
    __builtin_amdgcn_global_load_lds((gas_t)g, (las_t)l, 16, 0, 0);
}

// ---------------- f32 -> bf16 convert (8 elems/thread) ----------------
__global__ __launch_bounds__(256)
void conv_bf16_k(const float* __restrict__ in, ushort* __restrict__ out)
{
    const size_t i = ((size_t)blockIdx.x * 256 + threadIdx.x) * 8;
    float4 a = *(const float4*)(in + i);
    float4 b = *(const float4*)(in + i + 4);
    short8 o = {(short)f2bf(a.x), (short)f2bf(a.y), (short)f2bf(a.z), (short)f2bf(a.w),
                (short)f2bf(b.x), (short)f2bf(b.y), (short)f2bf(b.z), (short)f2bf(b.w)};
    *(short8*)(out + i) = o;
}

// ---------------- fused 5x Wt[n][k] = bf16(W[k][n]) ----------------
__global__ __launch_bounds__(256)
void transpose5_k(const float* __restrict__ W0, const float* __restrict__ W1,
                  const float* __restrict__ W2, const float* __restrict__ W3,
                  const float* __restrict__ W4, ushort* __restrict__ Wt)
{
    __shared__ float tile[32][33];
    const int z = blockIdx.z;
    const float* W = (z == 0) ? W0 : (z == 1) ? W1 : (z == 2) ? W2 : (z == 3) ? W3 : W4;
    ushort* dst = Wt + (size_t)z * 1024 * 1024;
    const int tx = threadIdx.x & 31;
    const int ty = threadIdx.x >> 5;   // 0..7
    const int n0 = blockIdx.x * 32;
    const int k0 = blockIdx.y * 32;
#pragma unroll
    for (int i = 0; i < 4; ++i)
        tile[ty + i * 8][tx] = W[(size_t)(k0 + ty + i * 8) * 1024 + n0 + tx];
    __syncthreads();
#pragma unroll
    for (int i = 0; i < 4; ++i)
        dst[(size_t)(n0 + ty + i * 8) * 1024 + k0 + tx] = f2bf(tile[tx][ty + i * 8]);
}

// ---------------- bias concat [bq;bk;bv] ----------------
__global__ __launch_bounds__(256)
void bias_concat_k(const float* __restrict__ b0, const float* __restrict__ b1,
                   const float* __restrict__ b2, float* __restrict__ out)
{
    const int i = blockIdx.x * 256 + threadIdx.x;   // 0..3071
    const int s = i >> 10;
    const int j = i & 1023;
    out[i] = (s == 0) ? b0[j] : (s == 1) ? b1[j] : b2[j];
}

// ======== 128x256 GEMM, BK=64, K=1024 (NT=16), 3-region LDS (R16) ========
// 512 thr = 8 waves (2x4); per-wave C: 64x64 (4x4 frags), acc 64 AGPR.
// LDS: A [3][128][64]=48KB + B [3][256][64]=96KB = 144KB -> 1 block/CU.
// Body t: STAGE(t+2) (6 gl_lds16); ds_read A8+B8 (b128); VMC(6) [forces
//   t+1]; lgkmcnt(0) [reads drained -> region overwrite safe]; s_barrier;
//   sched_barrier; 32 MFMA (2 k-halves). Tail: VMC(0)@t=14, none @t=15.

#define VMC(n) asm volatile("s_waitcnt vmcnt(" #n ")" ::: "memory")
#define KDIM 1024

template<int HAS_BIAS, int OUT_BF16>
__global__ __launch_bounds__(512, 2)
void gemm12_k(const ushort* __restrict__ A, const ushort* __restrict__ Bt,
              const float* __restrict__ bias, void* __restrict__ Cv,
              int N)
{
    __shared__ ushort As[3 * 8192];    // 48KB: [3][128][64]
    __shared__ ushort Bs[3 * 16384];   // 96KB: [3][256][64]
    const int tid = threadIdx.x;
    const int l = tid & 63;
    const int w = tid >> 6;
    const int wr = w >> 2;             // 0..1 (m 64-half)
    const int wc = w & 3;              // 0..3 (n 64-quarter)

    // XCD/L2-aware bijective remap (gx%4==0, gy%8==0)
    const int gx = gridDim.x;
    const int lin = blockIdx.y * gx + blockIdx.x;
    const int xcd = lin & 7;
    const int idx = lin >> 3;
    const int hb = gridDim.y >> 3;
    const int sxc = gx >> 2;
    const int g4 = idx >> 4;
    const int li = idx & 15;
    const int bx = (g4 % sxc) * 4 + (li & 3);
    const int by = xcd * hb + (g4 / sxc) * 4 + (li >> 2);
    const int bm = by * 128;
    const int bn = bx * 256;

    // staging: round covers 64 rows of 128B; thread row w*8+(l>>3), slot l&7;
    // pre-swizzled global col (row-term vanishes: rows ≡ 0 mod 8 per round):
    const int srow = w * 8 + (l >> 3);
    const int scol = ((l & 7) ^ ((l >> 3) & 7)) * 8;
    const ushort* Ag = A  + (size_t)(bm + srow) * KDIM + scol;
    const ushort* Bg = Bt + (size_t)(bn + srow) * KDIM + scol;
    const int lw = w * 512;            // ushort offset within a 4096-ushort round

    // frag reads: row base+lr (row&7 == l&7); phys slot = logical ^ (l&7)
    const int lr = l & 15;
    const int fb0 = (((l >> 4)) ^ (l & 7)) * 8;        // kh=0: logical slot l>>4
    const int fb1 = ((4 + (l >> 4)) ^ (l & 7)) * 8;    // kh=1: logical slot 4+(l>>4)
    const int laneA = (wr * 64 + lr) * 64;
    const int laneB = (wc * 64 + lr) * 64;

    f32x4 acc[4][4];
#pragma unroll
    for (int i = 0; i < 4; ++i)
#pragma unroll
        for (int n = 0; n < 4; ++n)
            acc[i][n] = (f32x4){0.f, 0.f, 0.f, 0.f};

#define STAGE12(tt, rg) do { \
    const size_t ko = (size_t)(tt) * 64; \
    ushort* ha = As + (rg) * 8192 + lw; \
    gl_lds16(Ag + ko, ha); \
    gl_lds16(Ag + (size_t)64 * KDIM + ko, ha + 4096); \
    ushort* hb2 = Bs + (rg) * 16384 + lw; \
    gl_lds16(Bg + ko, hb2); \
    gl_lds16(Bg + (size_t)64 * KDIM + ko, hb2 + 4096); \
    gl_lds16(Bg + (size_t)128 * KDIM + ko, hb2 + 8192); \
    gl_lds16(Bg + (size_t)192 * KDIM + ko, hb2 + 12288); \
} while (0)

    // prologue: stage t0->r0, t1->r1; VMC(6) lands t0; barrier
    STAGE12(0, 0);
    STAGE12(1, 1);
    VMC(6);
    __builtin_amdgcn_s_barrier();
    __builtin_amdgcn_sched_barrier(0);

#pragma unroll
    for (int t = 0; t < 16; ++t) {
        const int cur = t % 3;
        const int stg = (t + 2) % 3;
        if (t + 2 < 16) STAGE12(t + 2, stg);
        const ushort* ap = As + cur * 8192 + laneA;
        const ushort* bp = Bs + cur * 16384 + laneB;
        short8 af0[4], af1[4], bf0[4], bf1[4];
#pragma unroll
        for (int m = 0; m < 4; ++m) {
            af0[m] = *(const short8*)(ap + m * 1024 + fb0);
            af1[m] = *(const short8*)(ap + m * 1024 + fb1);
        }
#pragma unroll
        for (int n = 0; n < 4; ++n) {
            bf0[n] = *(const short8*)(bp + n * 1024 + fb0);
            bf1[n] = *(const short8*)(bp + n * 1024 + fb1);
        }
        if (t < 14) { VMC(6); }
        else if (t == 14) { VMC(0); }
        asm volatile("s_waitcnt lgkmcnt(0)" ::: "memory");
        __builtin_amdgcn_s_barrier();
        __builtin_amdgcn_sched_barrier(0);
#pragma unroll
        for (int m = 0; m < 4; ++m)
#pragma unroll
            for (int n = 0; n < 4; ++n)
                acc[m][n] = __builtin_amdgcn_mfma_f32_16x16x32_bf16(af0[m], bf0[n], acc[m][n], 0, 0, 0);
#pragma unroll
        for (int m = 0; m < 4; ++m)
#pragma unroll
            for (int n = 0; n < 4; ++n)
                acc[m][n] = __builtin_amdgcn_mfma_f32_16x16x32_bf16(af1[m], bf1[n], acc[m][n], 0, 0, 0);
    }
#undef STAGE12

    // epilogue: C/D layout col=lane&15, row=(lane>>4)*4+reg
    const int cr = (l >> 4) * 4;
    const int cc = l & 15;
    float bv[4];
#pragma unroll
    for (int n = 0; n < 4; ++n)
        bv[n] = HAS_BIAS ? bias[bn + wc * 64 + n * 16 + cc] : 0.f;
#pragma unroll
    for (int m = 0; m < 4; ++m) {
#pragma unroll
        for (int n = 0; n < 4; ++n) {
            const int col = bn + wc * 64 + n * 16 + cc;
#pragma unroll
            for (int r = 0; r < 4; ++r) {
                const int row = bm + wr * 64 + m * 16 + cr + r;
                float v = acc[m][n][r] + bv[n];
                if (OUT_BF16) ((ushort*)Cv)[(size_t)row * N + col] = f2bf(v);
                else          ((float*)Cv)[(size_t)row * N + col] = v;
            }
        }
    }
}

// ---------------- MFMA attention: 1 wave = 1 timestep (R7) ----------------
__global__ __launch_bounds__(256)
void attn2_k(const ushort* __restrict__ qkv, const ushort* __restrict__ pbuf,
             const float* __restrict__ ubias, const float* __restrict__ vbias,
             const int* __restrict__ masks, ushort* __restrict__ ctx)
{
    __shared__ __align__(16) float Pl[4][16 * 20];   // per-wave P tile, stride 20

    const int tid = threadIdx.x;
    const int w = tid >> 6;
    const int l = tid & 63;
    const int m = blockIdx.x * 4 + w;
    const int b2 = m >> 11;
    const int t2 = m & 2047;
    const int f  = m + 8;
    const int bs = f / 2049;
    const int ts = f - bs * 2049;
    const bool haspos = (ts != 0);
    const int mp = bs * 2048 + ts - 1;

    const int lr = l & 15;
    const int g  = l >> 4;
    const int ko = g * 8;

    const ushort* qb = qkv + (size_t)m * 3072;

    short8 quf[2], kf[2], qvf[2], pf[2];
#pragma unroll
    for (int c = 0; c < 2; ++c) {
        const int off = lr * 64 + c * 32 + ko;
        short8 q = *(const short8*)(qb + off);
        kf[c]    = *(const short8*)(qb + 1024 + off);
        float4 u0 = *(const float4*)(ubias + off);
        float4 u1 = *(const float4*)(ubias + off + 4);
        quf[c] = (short8){
            (short)f2bf(bf2f((ushort)q[0]) + u0.x), (short)f2bf(bf2f((ushort)q[1]) + u0.y),
            (short)f2bf(bf2f((ushort)q[2]) + u0.z), (short)f2bf(bf2f((ushort)q[3]) + u0.w),
            (short)f2bf(bf2f((ushort)q[4]) + u1.x), (short)f2bf(bf2f((ushort)q[5]) + u1.y),
            (short)f2bf(bf2f((ushort)q[6]) + u1.z), (short)f2bf(bf2f((ushort)q[7]) + u1.w)};
    }
    if (haspos) {
        const ushort* qmp = qkv + (size_t)mp * 3072;
        const ushort* pp  = pbuf + (size_t)mp * 1024;
#pragma unroll
        for (int c = 0; c < 2; ++c) {
            const int off = lr * 64 + c * 32 + ko;
            short8 q = *(const short8*)(qmp + off);
            pf[c]    = *(const short8*)(pp + off);
            float4 v0 = *(const float4*)(vbias + off);
            float4 v1 = *(const float4*)(vbias + off + 4);
            qvf[c] = (short8){
                (short)f2bf(bf2f((ushort)q[0]) + v0.x), (short)f2bf(bf2f((ushort)q[1]) + v0.y),
                (short)f2bf(bf2f((ushort)q[2]) + v0.z), (short)f2bf(bf2f((ushort)q[3]) + v0.w),
                (short)f2bf(bf2f((ushort)q[4]) + v1.x), (short)f2bf(bf2f((ushort)q[5]) + v1.y),
                (short)f2bf(bf2f((ushort)q[6]) + v1.z), (short)f2bf(bf2f((ushort)q[7]) + v1.w)};
        }
    }

    f32x4 s = (f32x4){0.f, 0.f, 0.f, 0.f};
    s = __builtin_amdgcn_mfma_f32_16x16x32_bf16(quf[0], kf[0], s, 0, 0, 0);
    s = __builtin_amdgcn_mfma_f32_16x16x32_bf16(quf[1], kf[1], s, 0, 0, 0);
    if (haspos) {
        s = __builtin_amdgcn_mfma_f32_16x16x32_bf16(qvf[0], pf[0], s, 0, 0, 0);
        s = __builtin_amdgcn_mfma_f32_16x16x32_bf16(qvf[1], pf[1], s, 0, 0, 0);
    }

    const bool mk = (masks[m] != 0);
    float sc[4];
#pragma unroll
    for (int r = 0; r < 4; ++r)
        sc[r] = mk ? s[r] * 0.03125f : 1e-9f;

    float mx[4], ex[4], sm[4];
#pragma unroll
    for (int r = 0; r < 4; ++r) {
        mx[r] = sc[r];
#pragma unroll
        for (int o = 8; o; o >>= 1) mx[r] = fmaxf(mx[r], __shfl_xor(mx[r], o, 64));
        ex[r] = __expf(sc[r] - mx[r]);
        sm[r] = ex[r];
#pragma unroll
        for (int o = 8; o; o >>= 1) sm[r] += __shfl_xor(sm[r], o, 64);
    }

    float* pw = Pl[w];
#pragma unroll
    for (int r = 0; r < 4; ++r)
        pw[(g * 4 + r) * 20 + lr] = ex[r] / sm[r];

    short8 pa;
    if (g < 2) {
        float4 p0 = *(const float4*)(pw + lr * 20 + g * 8);
        float4 p1 = *(const float4*)(pw + lr * 20 + g * 8 + 4);
        pa = (short8){(short)f2bf(p0.x), (short)f2bf(p0.y), (short)f2bf(p0.z), (short)f2bf(p0.w),
                      (short)f2bf(p1.x), (short)f2bf(p1.y), (short)f2bf(p1.z), (short)f2bf(p1.w)};
    } else {
        pa = (short8){0, 0, 0, 0, 0, 0, 0, 0};
    }

    const ushort* vb0 = qb + 2048;
    const size_t orow_base = (size_t)b2 * 2048 + (t2 >> 4);
    const int ocol_base = (t2 & 15) * 64;
#pragma unroll
    for (int n = 0; n < 4; ++n) {
        const int d0 = n * 16;
        short8 vf;
        if (g < 2) {
#pragma unroll
            for (int j = 0; j < 8; ++j)
                vf[j] = (short)vb0[(ko + j) * 64 + d0 + lr];
        } else {
            vf = (short8){0, 0, 0, 0, 0, 0, 0, 0};
        }
        f32x4 o = (f32x4){0.f, 0.f, 0.f, 0.f};
        o = __builtin_amdgcn_mfma_f32_16x16x32_bf16(pa, vf, o, 0, 0, 0);
#pragma unroll
        for (int r = 0; r < 4; ++r) {
            const int h1 = g * 4 + r;
            ctx[(orow_base + (size_t)h1 * 128) * 1024 + ocol_base + d0 + lr] = f2bf(o[r]);
        }
    }
}

extern "C" void kernel_launch(void* const* d_in, const int* in_sizes, int n_in,
                              void* d_out, int out_size, void* d_ws, size_t ws_size,
                              hipStream_t stream)
{
    (void)in_sizes; (void)n_in; (void)out_size; (void)ws_size;
    const float* inputs = (const float*)d_in[0];
    const float* pos    = (const float*)d_in[1];
    const int*   masks  = (const int*)d_in[2];
    const float* Wq = (const float*)d_in[3];
    const float* bq = (const float*)d_in[4];
    const float* Wk = (const float*)d_in[5];
    const float* bk = (const float*)d_in[6];
    const float* Wv = (const float*)d_in[7];
    const float* bv = (const float*)d_in[8];
    const float* Wp = (const float*)d_in[9];
    const float* Wo = (const float*)d_in[10];
    const float* bo = (const float*)d_in[11];
    const float* ub = (const float*)d_in[12];
    const float* vb = (const float*)d_in[13];

    // ws layout:
    //   [0,10MB)      WqT|WkT|WvT|WpT|WoT  (bf16 [N][K], contiguous)
    //   [10MB,+64KB)  biascat (f32[3072])
    //   S1 (32MB): pos_bf16 -> inputs_bf16 -> ctx
    //   S2 (32MB): pbuf  (pos @ Wp, bf16)
    //   S3 (96MB): qkv   ([16384][3072] bf16)
    char* ws = (char*)d_ws;
    const size_t WT_SZ = (size_t)1024 * 1024 * 2;
    ushort* WT  = (ushort*)(ws);                 // 5 consecutive transposed weights
    ushort* WqT = WT;
    ushort* WpT = (ushort*)(ws + 3 * WT_SZ);
    ushort* WoT = (ushort*)(ws + 4 * WT_SZ);
    float*  biascat = (float*)(ws + 5 * WT_SZ);
    char* bufs = ws + 5 * WT_SZ + 65536;
    const size_t S_SZ = (size_t)16384 * 1024 * 2;       // 32MB
    ushort* S1 = (ushort*)(bufs);
    ushort* S2 = (ushort*)(bufs + S_SZ);
    ushort* S3 = (ushort*)(bufs + 2 * S_SZ);            // 96MB

    dim3 blk(256);

    // fused weight transposes (z=0..4 -> Wq,Wk,Wv,Wp,Wo) + biases
    transpose5_k<<<dim3(32, 32, 5), blk, 0, stream>>>(Wq, Wk, Wv, Wp, Wo, WT);
    bias_concat_k<<<dim3(12), blk, 0, stream>>>(bq, bk, bv, biascat);

    conv_bf16_k<<<dim3(8192), blk, 0, stream>>>(pos, S1);
    gemm12_k<0, 1><<<dim3(4, 128), dim3(512), 0, stream>>>(S1, WpT, nullptr, S2, 1024);

    conv_bf16_k<<<dim3(8192), blk, 0, stream>>>(inputs, S1);
    gemm12_k<1, 1><<<dim3(12, 128), dim3(512), 0, stream>>>(S1, WqT, biascat, S3, 3072);

    attn2_k<<<dim3(4096), blk, 0, stream>>>(S3, S2, ub, vb, masks, S1);

    gemm12_k<1, 0><<<dim3(4, 128), dim3(512), 0, stream>>>(S1, WoT, bo, (float*)d_out, 1024);
}